// Round 1
// baseline (863.879 us; speedup 1.0000x reference)
//
#include <hip/hip_runtime.h>

// ---------------------------------------------------------------------------
// GraphMambaConv: N=32768 nodes, C=128, G=64 graphs x L=512, E=524288 edges,
// D_INNER=256, D_STATE=16, DT_RANK=8, D_CONV=4.  All fp32.
//
// Pipeline:
//  memset(stats, agg)
//  k_scatter   : agg[dst] += x[src]                      (atomics)
//  gemm<DUAL>  : h1_pre = agg@W_rel + b_rel + x@W_root + x   [stats S1]
//  gemm        : xz = x @ in_W            (32768 x 512)
//  k_conv      : xc = silu(causal_conv(xz[:, :256]))
//  gemm        : proj = xc @ xproj_W      (N=40)
//  k_dtbc      : dt = softplus(proj[:,:8]@dt_W + dt_b); B,C = proj slices
//  k_scan      : selective scan -> yg = (y + xc*Dp)*silu(z)   (yg aliases dt)
//  gemm        : p2 = yg @ out_W + x                      [stats S2]
//  k_fin12     : (a1,b1),(a2,b2) from S1,S2
//  k_add       : out = BN1(h1_pre) + BN2(p2)              [stats S3]
//  k_fin3_fold1: a3,b3 -> W1e = diag(a3)@W1, b1e = b3@W1 + mlp_b1
//  gemm        : g = gelu(out @ W1e + b1e)                [stats S4]
//  k_fin4_fold2: a4,b4 -> W2e, b2e
//  gemm        : out2 = g @ W2e + b2e + out               [stats S5]
//  k_fin5      : a5,b5
//  k_bn3       : d_out = out2*a5 + b5
// ---------------------------------------------------------------------------

#define NROWS 32768
#define CDIM  128
#define EDGES 524288
#define GL    512

// ---------------------------- scatter-add ---------------------------------
__global__ __launch_bounds__(256) void k_scatter(const float* __restrict__ x,
                                                 const int* __restrict__ ei,
                                                 float* __restrict__ agg)
{
    const int c  = threadIdx.x & 127;
    const int eo = threadIdx.x >> 7;
    const int ebase = blockIdx.x * 16;
#pragma unroll
    for (int i = 0; i < 8; ++i) {
        int e = ebase + i * 2 + eo;
        int s = ei[e];
        int d = ei[EDGES + e];
        atomicAdd(&agg[(size_t)d * CDIM + c], x[(size_t)s * CDIM + c]);
    }
}

// ------------------------------ GEMM core ---------------------------------
// out = epi( A0@W0 [+ A1@W1] [+bias] [+resid] ), optional column stats.
// A is MxK row-major (lda=K), W is KxN row-major (ldw), tile 64x64, 4x4/thread.
#define TM 64
#define TN 64
#define KB 32

template<bool DUAL, int ACT, bool STAT>
__global__ __launch_bounds__(256)
void gemm_k(const float* __restrict__ A0, const float* __restrict__ W0,
            const float* __restrict__ A1p, const float* __restrict__ W1p,
            int M, int N, int K, int ldw, int ldo,
            const float* __restrict__ bias,
            const float* __restrict__ resid, int ldr,
            float* __restrict__ outp,
            float* __restrict__ sumP, float* __restrict__ sqP)
{
    __shared__ __align__(16) float As[KB][TM];
    __shared__ __align__(16) float Bs[KB][TN];
    __shared__ float sB[2][TN];

    const int m0 = blockIdx.x * TM;
    const int n0 = blockIdx.y * TN;
    const int tid = threadIdx.x;
    const int tx = tid & 15;         // -> 4 cols
    const int ty = tid >> 4;         // -> 4 rows

    float acc[4][4];
#pragma unroll
    for (int i = 0; i < 4; ++i)
#pragma unroll
        for (int j = 0; j < 4; ++j) acc[i][j] = 0.f;

    const int npass = DUAL ? 2 : 1;
    for (int pass = 0; pass < npass; ++pass) {
        const float* A = (DUAL && pass) ? A1p : A0;
        const float* W = (DUAL && pass) ? W1p : W0;
        for (int k0 = 0; k0 < K; k0 += KB) {
            {   // A tile: rows m0..+64, cols k0..+32 ; store transposed
                int m = tid & 63, kg = tid >> 6;
                const float* src = A + (size_t)(m0 + m) * K + k0 + kg * 8;
                float4 v0 = *(const float4*)(src);
                float4 v1 = *(const float4*)(src + 4);
                int kb = kg * 8;
                As[kb + 0][m] = v0.x; As[kb + 1][m] = v0.y;
                As[kb + 2][m] = v0.z; As[kb + 3][m] = v0.w;
                As[kb + 4][m] = v1.x; As[kb + 5][m] = v1.y;
                As[kb + 6][m] = v1.z; As[kb + 7][m] = v1.w;
            }
            {   // W tile: rows k0..+32, cols n0..+64 (zero-pad n>=N)
                int n = tid & 63, kg = tid >> 6;
                int nn = n0 + n;
#pragma unroll
                for (int j = 0; j < 8; ++j) {
                    int k = k0 + kg * 8 + j;
                    Bs[kg * 8 + j][n] = (nn < N) ? W[(size_t)k * ldw + nn] : 0.f;
                }
            }
            __syncthreads();
#pragma unroll
            for (int kb = 0; kb < KB; ++kb) {
                const float4 av = *(const float4*)&As[kb][ty * 4];
                const float4 bv = *(const float4*)&Bs[kb][tx * 4];
                const float aa[4] = {av.x, av.y, av.z, av.w};
                const float bb[4] = {bv.x, bv.y, bv.z, bv.w};
#pragma unroll
                for (int i = 0; i < 4; ++i)
#pragma unroll
                    for (int j = 0; j < 4; ++j) acc[i][j] += aa[i] * bb[j];
            }
            __syncthreads();
        }
    }

    // ------------------------------ epilogue ------------------------------
    const int r0 = m0 + ty * 4;
    const int c0 = n0 + tx * 4;
    const bool cok = (c0 + 4 <= N);
    float cs[4] = {0.f, 0.f, 0.f, 0.f}, cq[4] = {0.f, 0.f, 0.f, 0.f};
    if (cok) {
        float bv[4] = {0.f, 0.f, 0.f, 0.f};
        if (bias) { float4 t = *(const float4*)&bias[c0];
                    bv[0] = t.x; bv[1] = t.y; bv[2] = t.z; bv[3] = t.w; }
#pragma unroll
        for (int i = 0; i < 4; ++i) {
            float v[4];
#pragma unroll
            for (int j = 0; j < 4; ++j) v[j] = acc[i][j] + bv[j];
            if (resid) {
                float4 rv = *(const float4*)&resid[(size_t)(r0 + i) * ldr + c0];
                v[0] += rv.x; v[1] += rv.y; v[2] += rv.z; v[3] += rv.w;
            }
            if (ACT == 1) {   // exact GELU
#pragma unroll
                for (int j = 0; j < 4; ++j)
                    v[j] = 0.5f * v[j] * (1.f + erff(v[j] * 0.7071067811865475f));
            }
            *(float4*)&outp[(size_t)(r0 + i) * ldo + c0] =
                make_float4(v[0], v[1], v[2], v[3]);
            if (STAT) {
#pragma unroll
                for (int j = 0; j < 4; ++j) { cs[j] += v[j]; cq[j] += v[j] * v[j]; }
            }
        }
    }
    if (STAT) {
        if (tid < TN) { sB[0][tid] = 0.f; sB[1][tid] = 0.f; }
        __syncthreads();
        if (cok) {
#pragma unroll
            for (int j = 0; j < 4; ++j) {
                atomicAdd(&sB[0][tx * 4 + j], cs[j]);
                atomicAdd(&sB[1][tx * 4 + j], cq[j]);
            }
        }
        __syncthreads();
        if (tid < TN && (n0 + tid) < N) {
            atomicAdd(&sumP[n0 + tid], sB[0][tid]);
            atomicAdd(&sqP[n0 + tid],  sB[1][tid]);
        }
    }
}

// --------------------------- causal conv + SiLU ----------------------------
__global__ __launch_bounds__(256) void k_conv(const float* __restrict__ xz,
                                              const float* __restrict__ cw,
                                              const float* __restrict__ cb,
                                              float* __restrict__ xc)
{
    const int r = blockIdx.x;        // global row
    const int l = r & (GL - 1);      // position within graph
    const int d = threadIdx.x;       // 0..255
    float4 w4 = *(const float4*)&cw[d * 4];
    const float taps[4] = {w4.x, w4.y, w4.z, w4.w};
    float acc = cb[d];
#pragma unroll
    for (int k = 0; k < 4; ++k) {
        int ll = l - 3 + k;
        if (ll >= 0) acc += xz[(size_t)(r - 3 + k) * 512 + d] * taps[k];
    }
    float s = 1.f / (1.f + __expf(-acc));
    xc[(size_t)r * 256 + d] = acc * s;
}

// ---------------- dt = softplus(proj[:,:8] @ dt_W + dt_b); B,C slices ------
__global__ __launch_bounds__(256) void k_dtbc(const float* __restrict__ proj,
                                              const float* __restrict__ dt_W,
                                              const float* __restrict__ dt_b,
                                              float* __restrict__ dtb,
                                              float* __restrict__ Bc,
                                              float* __restrict__ Cc)
{
    __shared__ float dtWS[8 * 256];
    __shared__ float dt_bS[256];
    __shared__ float projS[32 * 8];
    const int tid = threadIdx.x;
    const int r0 = blockIdx.x * 32;
    for (int i = tid; i < 2048; i += 256) dtWS[i] = dt_W[i];
    dt_bS[tid] = dt_b[tid];
    projS[tid] = proj[(size_t)(r0 + (tid >> 3)) * 40 + (tid & 7)];
    __syncthreads();

    const int c = tid;
    for (int rr = 0; rr < 32; ++rr) {
        float acc = dt_bS[c];
        const float* pr = &projS[rr * 8];
#pragma unroll
        for (int q = 0; q < 8; ++q) acc += pr[q] * dtWS[q * 256 + c];
        float sp = fmaxf(acc, 0.f) + log1pf(__expf(-fabsf(acc)));
        dtb[(size_t)(r0 + rr) * 256 + c] = sp;
    }
    // B = proj[:, 8:24], C = proj[:, 24:40]
    for (int e = tid; e < 1024; e += 256) {
        int rr = e >> 5, cc = e & 31;
        float v = proj[(size_t)(r0 + rr) * 40 + 8 + cc];
        if (cc < 16) Bc[(size_t)(r0 + rr) * 16 + cc] = v;
        else         Cc[(size_t)(r0 + rr) * 16 + cc - 16] = v;
    }
}

// ------------------------------ selective scan -----------------------------
// lane quad (sq=0..3) holds 4 states of one d-channel; 256 blocks = (g, dblk).
// NOTE: yg aliases dtb — each (r,d) slot is read (prefetch) strictly before
// the same lane-quad writes it; address sets across quads/blocks disjoint.
__global__ __launch_bounds__(256) void k_scan(const float* __restrict__ dtb,
                                              const float* __restrict__ xcb,
                                              const float* __restrict__ xzb,
                                              const float* __restrict__ Bb,
                                              const float* __restrict__ Cb,
                                              const float* __restrict__ A_log,
                                              const float* __restrict__ Dp,
                                              float* __restrict__ yg)
{
    const int g    = blockIdx.x >> 2;
    const int dblk = blockIdx.x & 3;
    const int tid  = threadIdx.x;
    const int dl = tid >> 2, sq = tid & 3;
    const int d = dblk * 64 + dl;

    float aA[4];
    {
        float4 t = *(const float4*)(A_log + d * 16 + sq * 4);
        aA[0] = -__expf(t.x); aA[1] = -__expf(t.y);
        aA[2] = -__expf(t.z); aA[3] = -__expf(t.w);
    }
    const float Dpd = Dp[d];
    float h[4] = {0.f, 0.f, 0.f, 0.f};

    size_t r = (size_t)g * GL;
    float dt_c = dtb[r * 256 + d];
    float xc_c = xcb[r * 256 + d];
    float z_c  = xzb[r * 512 + 256 + d];
    float Bv[4], Cv[4];
    {
        float4 b = *(const float4*)(Bb + r * 16 + sq * 4);
        float4 c = *(const float4*)(Cb + r * 16 + sq * 4);
        Bv[0]=b.x; Bv[1]=b.y; Bv[2]=b.z; Bv[3]=b.w;
        Cv[0]=c.x; Cv[1]=c.y; Cv[2]=c.z; Cv[3]=c.w;
    }

    for (int t = 0; t < GL; ++t) {
        const size_t rn = r + 1;
        float dt_n = 0.f, xc_n = 0.f, z_n = 0.f;
        float Bn[4] = {0,0,0,0}, Cn[4] = {0,0,0,0};
        if (t < GL - 1) {   // depth-1 prefetch
            dt_n = dtb[rn * 256 + d];
            xc_n = xcb[rn * 256 + d];
            z_n  = xzb[rn * 512 + 256 + d];
            float4 b = *(const float4*)(Bb + rn * 16 + sq * 4);
            float4 c = *(const float4*)(Cb + rn * 16 + sq * 4);
            Bn[0]=b.x; Bn[1]=b.y; Bn[2]=b.z; Bn[3]=b.w;
            Cn[0]=c.x; Cn[1]=c.y; Cn[2]=c.z; Cn[3]=c.w;
        }
        const float dtx = dt_c * xc_c;
        float y = 0.f;
#pragma unroll
        for (int j = 0; j < 4; ++j) {
            h[j] = h[j] * __expf(dt_c * aA[j]) + dtx * Bv[j];
            y += h[j] * Cv[j];
        }
        y += __shfl_xor(y, 1);
        y += __shfl_xor(y, 2);
        if (sq == 0) {
            float sz = z_c / (1.f + __expf(-z_c));
            yg[r * 256 + d] = (y + xc_c * Dpd) * sz;
        }
        dt_c = dt_n; xc_c = xc_n; z_c = z_n;
#pragma unroll
        for (int j = 0; j < 4; ++j) { Bv[j] = Bn[j]; Cv[j] = Cn[j]; }
        r = rn;
    }
}

// -------------------------- BN finalize / fold / add -----------------------
__global__ __launch_bounds__(256) void k_fin12(const float* __restrict__ st,
                                               const float* g1, const float* be1,
                                               const float* g2, const float* be2,
                                               float* __restrict__ ab)
{
    const int tid = threadIdx.x;
    const float inv = 1.f / 32768.f;
    if (tid < 128) {
        float m = st[tid] * inv, v = st[128 + tid] * inv - m * m;
        float a = g1[tid] * rsqrtf(v + 1e-5f);
        ab[tid] = a; ab[256 + tid] = be1[tid] - m * a;
    } else {
        int c = tid - 128;
        float m = st[256 + c] * inv, v = st[384 + c] * inv - m * m;
        float a = g2[c] * rsqrtf(v + 1e-5f);
        ab[512 + c] = a; ab[768 + c] = be2[c] - m * a;
    }
}

__global__ __launch_bounds__(256) void k_add(const float* __restrict__ h1p,
                                             const float* __restrict__ p2,
                                             const float* __restrict__ ab,
                                             float* __restrict__ outp,
                                             float* __restrict__ sumP,
                                             float* __restrict__ sqP)
{
    const int c = threadIdx.x & 127, half = threadIdx.x >> 7;
    const int rbase = blockIdx.x * 64 + half * 32;
    const float a1 = ab[c], b1 = ab[256 + c], a2 = ab[512 + c], b2 = ab[768 + c];
    float s = 0.f, q = 0.f;
    for (int i = 0; i < 32; ++i) {
        size_t idx = (size_t)(rbase + i) * 128 + c;
        float v = h1p[idx] * a1 + b1 + p2[idx] * a2 + b2;
        outp[idx] = v; s += v; q += v * v;
    }
    __shared__ float sh[2][2][128];
    sh[0][half][c] = s; sh[1][half][c] = q;
    __syncthreads();
    if (threadIdx.x < 128) {
        atomicAdd(&sumP[c], sh[0][0][c] + sh[0][1][c]);
        atomicAdd(&sqP[c],  sh[1][0][c] + sh[1][1][c]);
    }
}

__global__ __launch_bounds__(256) void k_fin3_fold1(
    const float* __restrict__ sumP, const float* __restrict__ sqP,
    const float* __restrict__ gam, const float* __restrict__ bet,
    const float* __restrict__ W1, const float* __restrict__ b1in,
    float* __restrict__ W1e, float* __restrict__ b1e)
{
    __shared__ float aS[128], bS[128];
    const int tid = threadIdx.x;
    const float inv = 1.f / 32768.f;
    if (tid < 128) {
        float m = sumP[tid] * inv, v = sqP[tid] * inv - m * m;
        float a = gam[tid] * rsqrtf(v + 1e-5f);
        aS[tid] = a; bS[tid] = bet[tid] - m * a;
    }
    __syncthreads();
    for (int e = tid; e < 128 * 256; e += 256) W1e[e] = aS[e >> 8] * W1[e];
    float acc = b1in[tid];
    for (int k = 0; k < 128; ++k) acc += bS[k] * W1[k * 256 + tid];
    b1e[tid] = acc;
}

__global__ __launch_bounds__(256) void k_fin4_fold2(
    const float* __restrict__ sumP, const float* __restrict__ sqP,
    const float* __restrict__ gam, const float* __restrict__ bet,
    const float* __restrict__ W2, const float* __restrict__ b2in,
    float* __restrict__ W2e, float* __restrict__ b2e)
{
    __shared__ float aS[256], bS[256];
    const int tid = threadIdx.x;
    const float inv = 1.f / 32768.f;
    {
        float m = sumP[tid] * inv, v = sqP[tid] * inv - m * m;
        float a = gam[tid] * rsqrtf(v + 1e-5f);
        aS[tid] = a; bS[tid] = bet[tid] - m * a;
    }
    __syncthreads();
    for (int e = tid; e < 256 * 128; e += 256) W2e[e] = aS[e >> 7] * W2[e];
    if (tid < 128) {
        float acc = b2in[tid];
        for (int k = 0; k < 256; ++k) acc += bS[k] * W2[k * 128 + tid];
        b2e[tid] = acc;
    }
}

__global__ __launch_bounds__(128) void k_fin5(const float* __restrict__ sumP,
                                              const float* __restrict__ sqP,
                                              const float* gam, const float* bet,
                                              float* __restrict__ ab)
{
    const int tid = threadIdx.x;
    if (tid < 128) {
        const float inv = 1.f / 32768.f;
        float m = sumP[tid] * inv, v = sqP[tid] * inv - m * m;
        float a = gam[tid] * rsqrtf(v + 1e-5f);
        ab[2048 + tid] = a; ab[2304 + tid] = bet[tid] - m * a;
    }
}

__global__ __launch_bounds__(256) void k_bn3(const float* __restrict__ out2,
                                             const float* __restrict__ ab,
                                             float* __restrict__ dout)
{
    size_t i4 = ((size_t)blockIdx.x * 256 + threadIdx.x) * 4;
    int c = (int)(i4 & 127);
    float4 v = *(const float4*)&out2[i4];
    float4 a = *(const float4*)&ab[2048 + c];
    float4 b = *(const float4*)&ab[2304 + c];
    v.x = v.x * a.x + b.x; v.y = v.y * a.y + b.y;
    v.z = v.z * a.z + b.z; v.w = v.w * a.w + b.w;
    *(float4*)&dout[i4] = v;
}

// ------------------------------- launch ------------------------------------
extern "C" void kernel_launch(void* const* d_in, const int* in_sizes, int n_in,
                              void* d_out, int out_size, void* d_ws, size_t ws_size,
                              hipStream_t stream)
{
    (void)in_sizes; (void)n_in; (void)out_size; (void)ws_size;
    const float* x      = (const float*)d_in[0];
    const int*   ei     = (const int*)d_in[1];
    // d_in[2] = batch (unused: equal-size sorted graphs == reshape)
    const float* W_root = (const float*)d_in[3];
    const float* W_rel  = (const float*)d_in[4];
    const float* b_rel  = (const float*)d_in[5];
    const float* n1_g = (const float*)d_in[6],  *n1_b = (const float*)d_in[7];
    const float* n2_g = (const float*)d_in[8],  *n2_b = (const float*)d_in[9];
    const float* n3_g = (const float*)d_in[10], *n3_b = (const float*)d_in[11];
    const float* m1_g = (const float*)d_in[12], *m1_b = (const float*)d_in[13];
    const float* W1   = (const float*)d_in[14], *b1   = (const float*)d_in[15];
    const float* m2_g = (const float*)d_in[16], *m2_b = (const float*)d_in[17];
    const float* W2   = (const float*)d_in[18], *b2   = (const float*)d_in[19];
    const float* in_W   = (const float*)d_in[20];
    const float* conv_w = (const float*)d_in[21], *conv_b = (const float*)d_in[22];
    const float* xproj_W= (const float*)d_in[23];
    const float* dt_W   = (const float*)d_in[24], *dt_b = (const float*)d_in[25];
    const float* A_log  = (const float*)d_in[26], *Dp   = (const float*)d_in[27];
    const float* out_W  = (const float*)d_in[28];

    float* ws = (float*)d_ws;
    // small region
    float* st  = ws;             // 2048 used (S1..S5 sums/sumsqs)
    float* ab  = ws + 4096;      // a/b affine params
    float* W1e = ws + 8192;      // 128*256
    float* b1e = W1e + 32768;    // 256
    float* W2e = ws + 41216;     // 256*128
    float* b2e = W2e + 32768;    // 128
    // big buffers (base aligned; ~194 MB total)
    float* big  = ws + 74752;
    float* agg  = big;                    // 4194304 (later reused as p2)
    float* p2   = agg;
    float* h1p  = big + 4194304;          // 4194304
    float* xz   = big + 8388608;          // 16777216 (later: g + out2)
    float* gbuf = xz;
    float* out2 = xz + 8388608;
    float* xc   = big + 25165824;         // 8388608
    float* proj = big + 33554432;         // 1310720
    float* dtb  = big + 34865152;         // 8388608 (yg aliases dtb)
    float* ygb  = dtb;
    float* Bc   = big + 43253760;         // 524288
    float* Cc   = big + 43778048;         // 524288
    float* outb = big + 44302336;         // 4194304

    hipMemsetAsync(st, 0, 2048 * sizeof(float), stream);
    hipMemsetAsync(agg, 0, (size_t)4194304 * sizeof(float), stream);

    k_scatter<<<32768, 256, 0, stream>>>(x, ei, agg);
    // h1_pre = agg@W_rel + b_rel + x@W_root + x  [S1]
    gemm_k<true, 0, true><<<dim3(512, 2), 256, 0, stream>>>(
        agg, W_rel, x, W_root, NROWS, 128, 128, 128, 128,
        b_rel, x, 128, h1p, st + 0, st + 128);
    // xz = x @ in_W
    gemm_k<false, 0, false><<<dim3(512, 8), 256, 0, stream>>>(
        x, in_W, nullptr, nullptr, NROWS, 512, 128, 512, 512,
        nullptr, nullptr, 0, xz, nullptr, nullptr);
    k_conv<<<32768, 256, 0, stream>>>(xz, conv_w, conv_b, xc);
    // proj = xc @ xproj_W (N=40)
    gemm_k<false, 0, false><<<dim3(512, 1), 256, 0, stream>>>(
        xc, xproj_W, nullptr, nullptr, NROWS, 40, 256, 40, 40,
        nullptr, nullptr, 0, proj, nullptr, nullptr);
    k_dtbc<<<1024, 256, 0, stream>>>(proj, dt_W, dt_b, dtb, Bc, Cc);
    k_scan<<<256, 256, 0, stream>>>(dtb, xc, xz, Bc, Cc, A_log, Dp, ygb);
    // p2 = yg @ out_W + x  [S2]
    gemm_k<false, 0, true><<<dim3(512, 2), 256, 0, stream>>>(
        ygb, out_W, nullptr, nullptr, NROWS, 128, 256, 128, 128,
        nullptr, x, 128, p2, st + 256, st + 384);
    k_fin12<<<1, 256, 0, stream>>>(st, n1_g, n1_b, n2_g, n2_b, ab);
    // out = BN1(h1_pre) + BN2(p2)  [S3]
    k_add<<<512, 256, 0, stream>>>(h1p, p2, ab, outb, st + 512, st + 640);
    k_fin3_fold1<<<1, 256, 0, stream>>>(st + 512, st + 640, m1_g, m1_b, W1, b1, W1e, b1e);
    // g = gelu(out @ W1e + b1e)  [S4]
    gemm_k<false, 1, true><<<dim3(512, 4), 256, 0, stream>>>(
        outb, W1e, nullptr, nullptr, NROWS, 256, 128, 256, 256,
        b1e, nullptr, 0, gbuf, st + 768, st + 1024);
    k_fin4_fold2<<<1, 256, 0, stream>>>(st + 768, st + 1024, m2_g, m2_b, W2, b2, W2e, b2e);
    // out2 = g @ W2e + b2e + out  [S5]
    gemm_k<false, 0, true><<<dim3(512, 2), 256, 0, stream>>>(
        gbuf, W2e, nullptr, nullptr, NROWS, 128, 256, 128, 128,
        b2e, outb, 128, out2, st + 1280, st + 1408);
    k_fin5<<<1, 128, 0, stream>>>(st + 1280, st + 1408, n3_g, n3_b, ab);
    k_bn3<<<4096, 256, 0, stream>>>(out2, ab, (float*)d_out);
}

// Round 2
// 751.366 us; speedup vs baseline: 1.1497x; 1.1497x over previous
//
#include <hip/hip_runtime.h>

// ---------------------------------------------------------------------------
// GraphMambaConv: N=32768 nodes, C=128, G=64 graphs x L=512, E=524288 edges,
// D_INNER=256, D_STATE=16, DT_RANK=8, D_CONV=4.  All fp32.
//
// Round 2: replace atomic scatter (215us, atomic-bound, 268MB write-through)
// with CSR build + per-node gather (writes 16.8MB once, x reads L2-resident).
// ---------------------------------------------------------------------------

#define NROWS 32768
#define CDIM  128
#define EDGES 524288
#define GL    512

// ------------------------- CSR build: histogram ----------------------------
__global__ __launch_bounds__(256) void k_hist(const int* __restrict__ ei,
                                              int* __restrict__ deg)
{
    const int e = blockIdx.x * 1024 + threadIdx.x * 4;
    const int4 d4 = *(const int4*)&ei[EDGES + e];
    atomicAdd(&deg[d4.x], 1);
    atomicAdd(&deg[d4.y], 1);
    atomicAdd(&deg[d4.z], 1);
    atomicAdd(&deg[d4.w], 1);
}

// ---------------- CSR build: exclusive prefix scan (1 block) ---------------
__global__ __launch_bounds__(1024) void k_scanidx(const int* __restrict__ deg,
                                                  int* __restrict__ base,
                                                  int* __restrict__ cursor)
{
    __shared__ int ps[1024];
    const int tid = threadIdx.x;
    int loc[32];
    int s = 0;
#pragma unroll
    for (int i = 0; i < 32; ++i) { loc[i] = deg[tid * 32 + i]; s += loc[i]; }
    ps[tid] = s;
    __syncthreads();
    for (int off = 1; off < 1024; off <<= 1) {
        int v = (tid >= off) ? ps[tid - off] : 0;
        __syncthreads();
        ps[tid] += v;
        __syncthreads();
    }
    int run = tid ? ps[tid - 1] : 0;
#pragma unroll
    for (int i = 0; i < 32; ++i) {
        base[tid * 32 + i] = run;
        cursor[tid * 32 + i] = run;
        run += loc[i];
    }
    if (tid == 0) base[32768] = EDGES;
}

// ------------------------- CSR build: fill src lists -----------------------
__global__ __launch_bounds__(256) void k_fill(const int* __restrict__ ei,
                                              int* __restrict__ cursor,
                                              int* __restrict__ srcs)
{
    const int e = blockIdx.x * 1024 + threadIdx.x * 4;
    const int4 s4 = *(const int4*)&ei[e];
    const int4 d4 = *(const int4*)&ei[EDGES + e];
    int p;
    p = atomicAdd(&cursor[d4.x], 1); srcs[p] = s4.x;
    p = atomicAdd(&cursor[d4.y], 1); srcs[p] = s4.y;
    p = atomicAdd(&cursor[d4.z], 1); srcs[p] = s4.z;
    p = atomicAdd(&cursor[d4.w], 1); srcs[p] = s4.w;
}

// ------------------------- gather: one wave per node ------------------------
__global__ __launch_bounds__(256) void k_gather(const float* __restrict__ x,
                                                const int* __restrict__ base,
                                                const int* __restrict__ srcs,
                                                float* __restrict__ agg)
{
    const int node = blockIdx.x * 4 + (threadIdx.x >> 6);
    const int lane = threadIdx.x & 63;
    const int b0 = base[node], b1 = base[node + 1];
    float2 a0 = make_float2(0.f, 0.f), a1 = make_float2(0.f, 0.f);
    int i = b0;
    for (; i + 2 <= b1; i += 2) {
        const int s0 = srcs[i], s1 = srcs[i + 1];
        const float2 v0 = *(const float2*)&x[(size_t)s0 * 128 + lane * 2];
        const float2 v1 = *(const float2*)&x[(size_t)s1 * 128 + lane * 2];
        a0.x += v0.x; a0.y += v0.y;
        a1.x += v1.x; a1.y += v1.y;
    }
    if (i < b1) {
        const int s0 = srcs[i];
        const float2 v0 = *(const float2*)&x[(size_t)s0 * 128 + lane * 2];
        a0.x += v0.x; a0.y += v0.y;
    }
    a0.x += a1.x; a0.y += a1.y;
    *(float2*)&agg[(size_t)node * 128 + lane * 2] = a0;
}

// ------------------------------ GEMM core ---------------------------------
// out = epi( A0@W0 [+ A1@W1] [+bias] [+resid] ), optional column stats.
// A is MxK row-major (lda=K), W is KxN row-major (ldw), tile 64x64, 4x4/thread.
#define TM 64
#define TN 64
#define KB 32

template<bool DUAL, int ACT, bool STAT>
__global__ __launch_bounds__(256)
void gemm_k(const float* __restrict__ A0, const float* __restrict__ W0,
            const float* __restrict__ A1p, const float* __restrict__ W1p,
            int M, int N, int K, int ldw, int ldo,
            const float* __restrict__ bias,
            const float* __restrict__ resid, int ldr,
            float* __restrict__ outp,
            float* __restrict__ sumP, float* __restrict__ sqP)
{
    __shared__ __align__(16) float As[KB][TM];
    __shared__ __align__(16) float Bs[KB][TN];
    __shared__ float sB[2][TN];

    const int m0 = blockIdx.x * TM;
    const int n0 = blockIdx.y * TN;
    const int tid = threadIdx.x;
    const int tx = tid & 15;         // -> 4 cols
    const int ty = tid >> 4;         // -> 4 rows

    float acc[4][4];
#pragma unroll
    for (int i = 0; i < 4; ++i)
#pragma unroll
        for (int j = 0; j < 4; ++j) acc[i][j] = 0.f;

    const int npass = DUAL ? 2 : 1;
    for (int pass = 0; pass < npass; ++pass) {
        const float* A = (DUAL && pass) ? A1p : A0;
        const float* W = (DUAL && pass) ? W1p : W0;
        for (int k0 = 0; k0 < K; k0 += KB) {
            {   // A tile: rows m0..+64, cols k0..+32 ; store transposed
                int m = tid & 63, kg = tid >> 6;
                const float* src = A + (size_t)(m0 + m) * K + k0 + kg * 8;
                float4 v0 = *(const float4*)(src);
                float4 v1 = *(const float4*)(src + 4);
                int kb = kg * 8;
                As[kb + 0][m] = v0.x; As[kb + 1][m] = v0.y;
                As[kb + 2][m] = v0.z; As[kb + 3][m] = v0.w;
                As[kb + 4][m] = v1.x; As[kb + 5][m] = v1.y;
                As[kb + 6][m] = v1.z; As[kb + 7][m] = v1.w;
            }
            {   // W tile: rows k0..+32, cols n0..+64 (zero-pad n>=N)
                int n = tid & 63, kg = tid >> 6;
                int nn = n0 + n;
#pragma unroll
                for (int j = 0; j < 8; ++j) {
                    int k = k0 + kg * 8 + j;
                    Bs[kg * 8 + j][n] = (nn < N) ? W[(size_t)k * ldw + nn] : 0.f;
                }
            }
            __syncthreads();
#pragma unroll
            for (int kb = 0; kb < KB; ++kb) {
                const float4 av = *(const float4*)&As[kb][ty * 4];
                const float4 bv = *(const float4*)&Bs[kb][tx * 4];
                const float aa[4] = {av.x, av.y, av.z, av.w};
                const float bb[4] = {bv.x, bv.y, bv.z, bv.w};
#pragma unroll
                for (int i = 0; i < 4; ++i)
#pragma unroll
                    for (int j = 0; j < 4; ++j) acc[i][j] += aa[i] * bb[j];
            }
            __syncthreads();
        }
    }

    // ------------------------------ epilogue ------------------------------
    const int r0 = m0 + ty * 4;
    const int c0 = n0 + tx * 4;
    const bool cok = (c0 + 4 <= N);
    float cs[4] = {0.f, 0.f, 0.f, 0.f}, cq[4] = {0.f, 0.f, 0.f, 0.f};
    if (cok) {
        float bv[4] = {0.f, 0.f, 0.f, 0.f};
        if (bias) { float4 t = *(const float4*)&bias[c0];
                    bv[0] = t.x; bv[1] = t.y; bv[2] = t.z; bv[3] = t.w; }
#pragma unroll
        for (int i = 0; i < 4; ++i) {
            float v[4];
#pragma unroll
            for (int j = 0; j < 4; ++j) v[j] = acc[i][j] + bv[j];
            if (resid) {
                float4 rv = *(const float4*)&resid[(size_t)(r0 + i) * ldr + c0];
                v[0] += rv.x; v[1] += rv.y; v[2] += rv.z; v[3] += rv.w;
            }
            if (ACT == 1) {   // exact GELU
#pragma unroll
                for (int j = 0; j < 4; ++j)
                    v[j] = 0.5f * v[j] * (1.f + erff(v[j] * 0.7071067811865475f));
            }
            *(float4*)&outp[(size_t)(r0 + i) * ldo + c0] =
                make_float4(v[0], v[1], v[2], v[3]);
            if (STAT) {
#pragma unroll
                for (int j = 0; j < 4; ++j) { cs[j] += v[j]; cq[j] += v[j] * v[j]; }
            }
        }
    }
    if (STAT) {
        if (tid < TN) { sB[0][tid] = 0.f; sB[1][tid] = 0.f; }
        __syncthreads();
        if (cok) {
#pragma unroll
            for (int j = 0; j < 4; ++j) {
                atomicAdd(&sB[0][tx * 4 + j], cs[j]);
                atomicAdd(&sB[1][tx * 4 + j], cq[j]);
            }
        }
        __syncthreads();
        if (tid < TN && (n0 + tid) < N) {
            atomicAdd(&sumP[n0 + tid], sB[0][tid]);
            atomicAdd(&sqP[n0 + tid],  sB[1][tid]);
        }
    }
}

// --------------------------- causal conv + SiLU ----------------------------
__global__ __launch_bounds__(256) void k_conv(const float* __restrict__ xz,
                                              const float* __restrict__ cw,
                                              const float* __restrict__ cb,
                                              float* __restrict__ xc)
{
    const int r = blockIdx.x;        // global row
    const int l = r & (GL - 1);      // position within graph
    const int d = threadIdx.x;       // 0..255
    float4 w4 = *(const float4*)&cw[d * 4];
    const float taps[4] = {w4.x, w4.y, w4.z, w4.w};
    float acc = cb[d];
#pragma unroll
    for (int k = 0; k < 4; ++k) {
        int ll = l - 3 + k;
        if (ll >= 0) acc += xz[(size_t)(r - 3 + k) * 512 + d] * taps[k];
    }
    float s = 1.f / (1.f + __expf(-acc));
    xc[(size_t)r * 256 + d] = acc * s;
}

// ---------------- dt = softplus(proj[:,:8] @ dt_W + dt_b); B,C slices ------
__global__ __launch_bounds__(256) void k_dtbc(const float* __restrict__ proj,
                                              const float* __restrict__ dt_W,
                                              const float* __restrict__ dt_b,
                                              float* __restrict__ dtb,
                                              float* __restrict__ Bc,
                                              float* __restrict__ Cc)
{
    __shared__ float dtWS[8 * 256];
    __shared__ float dt_bS[256];
    __shared__ float projS[32 * 8];
    const int tid = threadIdx.x;
    const int r0 = blockIdx.x * 32;
    for (int i = tid; i < 2048; i += 256) dtWS[i] = dt_W[i];
    dt_bS[tid] = dt_b[tid];
    projS[tid] = proj[(size_t)(r0 + (tid >> 3)) * 40 + (tid & 7)];
    __syncthreads();

    const int c = tid;
    for (int rr = 0; rr < 32; ++rr) {
        float acc = dt_bS[c];
        const float* pr = &projS[rr * 8];
#pragma unroll
        for (int q = 0; q < 8; ++q) acc += pr[q] * dtWS[q * 256 + c];
        float sp = fmaxf(acc, 0.f) + log1pf(__expf(-fabsf(acc)));
        dtb[(size_t)(r0 + rr) * 256 + c] = sp;
    }
    // B = proj[:, 8:24], C = proj[:, 24:40]
    for (int e = tid; e < 1024; e += 256) {
        int rr = e >> 5, cc = e & 31;
        float v = proj[(size_t)(r0 + rr) * 40 + 8 + cc];
        if (cc < 16) Bc[(size_t)(r0 + rr) * 16 + cc] = v;
        else         Cc[(size_t)(r0 + rr) * 16 + cc - 16] = v;
    }
}

// ------------------------------ selective scan -----------------------------
// lane quad (sq=0..3) holds 4 states of one d-channel; 256 blocks = (g, dblk).
// NOTE: yg aliases dtb — each (r,d) slot is read (prefetch) strictly before
// the same lane-quad writes it; address sets across quads/blocks disjoint.
__global__ __launch_bounds__(256) void k_scan(const float* __restrict__ dtb,
                                              const float* __restrict__ xcb,
                                              const float* __restrict__ xzb,
                                              const float* __restrict__ Bb,
                                              const float* __restrict__ Cb,
                                              const float* __restrict__ A_log,
                                              const float* __restrict__ Dp,
                                              float* __restrict__ yg)
{
    const int g    = blockIdx.x >> 2;
    const int dblk = blockIdx.x & 3;
    const int tid  = threadIdx.x;
    const int dl = tid >> 2, sq = tid & 3;
    const int d = dblk * 64 + dl;

    float aA[4];
    {
        float4 t = *(const float4*)(A_log + d * 16 + sq * 4);
        aA[0] = -__expf(t.x); aA[1] = -__expf(t.y);
        aA[2] = -__expf(t.z); aA[3] = -__expf(t.w);
    }
    const float Dpd = Dp[d];
    float h[4] = {0.f, 0.f, 0.f, 0.f};

    size_t r = (size_t)g * GL;
    float dt_c = dtb[r * 256 + d];
    float xc_c = xcb[r * 256 + d];
    float z_c  = xzb[r * 512 + 256 + d];
    float Bv[4], Cv[4];
    {
        float4 b = *(const float4*)(Bb + r * 16 + sq * 4);
        float4 c = *(const float4*)(Cb + r * 16 + sq * 4);
        Bv[0]=b.x; Bv[1]=b.y; Bv[2]=b.z; Bv[3]=b.w;
        Cv[0]=c.x; Cv[1]=c.y; Cv[2]=c.z; Cv[3]=c.w;
    }

    for (int t = 0; t < GL; ++t) {
        const size_t rn = r + 1;
        float dt_n = 0.f, xc_n = 0.f, z_n = 0.f;
        float Bn[4] = {0,0,0,0}, Cn[4] = {0,0,0,0};
        if (t < GL - 1) {   // depth-1 prefetch
            dt_n = dtb[rn * 256 + d];
            xc_n = xcb[rn * 256 + d];
            z_n  = xzb[rn * 512 + 256 + d];
            float4 b = *(const float4*)(Bb + rn * 16 + sq * 4);
            float4 c = *(const float4*)(Cb + rn * 16 + sq * 4);
            Bn[0]=b.x; Bn[1]=b.y; Bn[2]=b.z; Bn[3]=b.w;
            Cn[0]=c.x; Cn[1]=c.y; Cn[2]=c.z; Cn[3]=c.w;
        }
        const float dtx = dt_c * xc_c;
        float y = 0.f;
#pragma unroll
        for (int j = 0; j < 4; ++j) {
            h[j] = h[j] * __expf(dt_c * aA[j]) + dtx * Bv[j];
            y += h[j] * Cv[j];
        }
        y += __shfl_xor(y, 1);
        y += __shfl_xor(y, 2);
        if (sq == 0) {
            float sz = z_c / (1.f + __expf(-z_c));
            yg[r * 256 + d] = (y + xc_c * Dpd) * sz;
        }
        dt_c = dt_n; xc_c = xc_n; z_c = z_n;
#pragma unroll
        for (int j = 0; j < 4; ++j) { Bv[j] = Bn[j]; Cv[j] = Cn[j]; }
        r = rn;
    }
}

// -------------------------- BN finalize / fold / add -----------------------
__global__ __launch_bounds__(256) void k_fin12(const float* __restrict__ st,
                                               const float* g1, const float* be1,
                                               const float* g2, const float* be2,
                                               float* __restrict__ ab)
{
    const int tid = threadIdx.x;
    const float inv = 1.f / 32768.f;
    if (tid < 128) {
        float m = st[tid] * inv, v = st[128 + tid] * inv - m * m;
        float a = g1[tid] * rsqrtf(v + 1e-5f);
        ab[tid] = a; ab[256 + tid] = be1[tid] - m * a;
    } else {
        int c = tid - 128;
        float m = st[256 + c] * inv, v = st[384 + c] * inv - m * m;
        float a = g2[c] * rsqrtf(v + 1e-5f);
        ab[512 + c] = a; ab[768 + c] = be2[c] - m * a;
    }
}

__global__ __launch_bounds__(256) void k_add(const float* __restrict__ h1p,
                                             const float* __restrict__ p2,
                                             const float* __restrict__ ab,
                                             float* __restrict__ outp,
                                             float* __restrict__ sumP,
                                             float* __restrict__ sqP)
{
    const int c = threadIdx.x & 127, half = threadIdx.x >> 7;
    const int rbase = blockIdx.x * 64 + half * 32;
    const float a1 = ab[c], b1 = ab[256 + c], a2 = ab[512 + c], b2 = ab[768 + c];
    float s = 0.f, q = 0.f;
    for (int i = 0; i < 32; ++i) {
        size_t idx = (size_t)(rbase + i) * 128 + c;
        float v = h1p[idx] * a1 + b1 + p2[idx] * a2 + b2;
        outp[idx] = v; s += v; q += v * v;
    }
    __shared__ float sh[2][2][128];
    sh[0][half][c] = s; sh[1][half][c] = q;
    __syncthreads();
    if (threadIdx.x < 128) {
        atomicAdd(&sumP[c], sh[0][0][c] + sh[0][1][c]);
        atomicAdd(&sqP[c],  sh[1][0][c] + sh[1][1][c]);
    }
}

__global__ __launch_bounds__(256) void k_fin3_fold1(
    const float* __restrict__ sumP, const float* __restrict__ sqP,
    const float* __restrict__ gam, const float* __restrict__ bet,
    const float* __restrict__ W1, const float* __restrict__ b1in,
    float* __restrict__ W1e, float* __restrict__ b1e)
{
    __shared__ float aS[128], bS[128];
    const int tid = threadIdx.x;
    const float inv = 1.f / 32768.f;
    if (tid < 128) {
        float m = sumP[tid] * inv, v = sqP[tid] * inv - m * m;
        float a = gam[tid] * rsqrtf(v + 1e-5f);
        aS[tid] = a; bS[tid] = bet[tid] - m * a;
    }
    __syncthreads();
    for (int e = tid; e < 128 * 256; e += 256) W1e[e] = aS[e >> 8] * W1[e];
    float acc = b1in[tid];
    for (int k = 0; k < 128; ++k) acc += bS[k] * W1[k * 256 + tid];
    b1e[tid] = acc;
}

__global__ __launch_bounds__(256) void k_fin4_fold2(
    const float* __restrict__ sumP, const float* __restrict__ sqP,
    const float* __restrict__ gam, const float* __restrict__ bet,
    const float* __restrict__ W2, const float* __restrict__ b2in,
    float* __restrict__ W2e, float* __restrict__ b2e)
{
    __shared__ float aS[256], bS[256];
    const int tid = threadIdx.x;
    const float inv = 1.f / 32768.f;
    {
        float m = sumP[tid] * inv, v = sqP[tid] * inv - m * m;
        float a = gam[tid] * rsqrtf(v + 1e-5f);
        aS[tid] = a; bS[tid] = bet[tid] - m * a;
    }
    __syncthreads();
    for (int e = tid; e < 256 * 128; e += 256) W2e[e] = aS[e >> 7] * W2[e];
    if (tid < 128) {
        float acc = b2in[tid];
        for (int k = 0; k < 256; ++k) acc += bS[k] * W2[k * 128 + tid];
        b2e[tid] = acc;
    }
}

__global__ __launch_bounds__(128) void k_fin5(const float* __restrict__ sumP,
                                              const float* __restrict__ sqP,
                                              const float* gam, const float* bet,
                                              float* __restrict__ ab)
{
    const int tid = threadIdx.x;
    if (tid < 128) {
        const float inv = 1.f / 32768.f;
        float m = sumP[tid] * inv, v = sqP[tid] * inv - m * m;
        float a = gam[tid] * rsqrtf(v + 1e-5f);
        ab[2048 + tid] = a; ab[2304 + tid] = bet[tid] - m * a;
    }
}

__global__ __launch_bounds__(256) void k_bn3(const float* __restrict__ out2,
                                             const float* __restrict__ ab,
                                             float* __restrict__ dout)
{
    size_t i4 = ((size_t)blockIdx.x * 256 + threadIdx.x) * 4;
    int c = (int)(i4 & 127);
    float4 v = *(const float4*)&out2[i4];
    float4 a = *(const float4*)&ab[2048 + c];
    float4 b = *(const float4*)&ab[2304 + c];
    v.x = v.x * a.x + b.x; v.y = v.y * a.y + b.y;
    v.z = v.z * a.z + b.z; v.w = v.w * a.w + b.w;
    *(float4*)&dout[i4] = v;
}

// ------------------------------- launch ------------------------------------
extern "C" void kernel_launch(void* const* d_in, const int* in_sizes, int n_in,
                              void* d_out, int out_size, void* d_ws, size_t ws_size,
                              hipStream_t stream)
{
    (void)in_sizes; (void)n_in; (void)out_size; (void)ws_size;
    const float* x      = (const float*)d_in[0];
    const int*   ei     = (const int*)d_in[1];
    // d_in[2] = batch (unused: equal-size sorted graphs == reshape)
    const float* W_root = (const float*)d_in[3];
    const float* W_rel  = (const float*)d_in[4];
    const float* b_rel  = (const float*)d_in[5];
    const float* n1_g = (const float*)d_in[6],  *n1_b = (const float*)d_in[7];
    const float* n2_g = (const float*)d_in[8],  *n2_b = (const float*)d_in[9];
    const float* n3_g = (const float*)d_in[10], *n3_b = (const float*)d_in[11];
    const float* m1_g = (const float*)d_in[12], *m1_b = (const float*)d_in[13];
    const float* W1   = (const float*)d_in[14], *b1   = (const float*)d_in[15];
    const float* m2_g = (const float*)d_in[16], *m2_b = (const float*)d_in[17];
    const float* W2   = (const float*)d_in[18], *b2   = (const float*)d_in[19];
    const float* in_W   = (const float*)d_in[20];
    const float* conv_w = (const float*)d_in[21], *conv_b = (const float*)d_in[22];
    const float* xproj_W= (const float*)d_in[23];
    const float* dt_W   = (const float*)d_in[24], *dt_b = (const float*)d_in[25];
    const float* A_log  = (const float*)d_in[26], *Dp   = (const float*)d_in[27];
    const float* out_W  = (const float*)d_in[28];

    float* ws = (float*)d_ws;
    // small region
    float* st  = ws;             // 2048 used (S1..S5 sums/sumsqs)
    float* ab  = ws + 4096;      // a/b affine params
    float* W1e = ws + 8192;      // 128*256
    float* b1e = W1e + 32768;    // 256
    float* W2e = ws + 41216;     // 256*128
    float* b2e = W2e + 32768;    // 128
    // big buffers (base aligned; ~194 MB total)
    float* big  = ws + 74752;
    float* agg  = big;                    // 4194304 (later reused as p2)
    float* p2   = agg;
    float* h1p  = big + 4194304;          // 4194304
    float* xz   = big + 8388608;          // 16777216 (later: g + out2)
    float* gbuf = xz;
    float* out2 = xz + 8388608;
    float* xc   = big + 25165824;         // 8388608
    float* proj = big + 33554432;         // 1310720
    float* dtb  = big + 34865152;         // 8388608 (yg aliases dtb)
    float* ygb  = dtb;
    float* Bc   = big + 43253760;         // 524288
    float* Cc   = big + 43778048;         // 524288
    float* outb = big + 44302336;         // 4194304

    // CSR scratch lives in the h1p region (dead until the h1 GEMM writes it):
    // gather (last CSR reader) completes before gemm h1 (first h1p writer).
    int* ideg   = (int*)h1p;              // 32768
    int* ibase  = ideg + 32768;           // 32769
    int* icur   = ideg + 65552;           // 32768 (16B-aligned)
    int* isrcs  = ideg + 98320;           // 524288

    hipMemsetAsync(st, 0, 2048 * sizeof(float), stream);
    hipMemsetAsync(ideg, 0, 32768 * sizeof(int), stream);

    // ---- CSR build + gather (replaces atomic scatter) ----
    k_hist<<<512, 256, 0, stream>>>(ei, ideg);
    k_scanidx<<<1, 1024, 0, stream>>>(ideg, ibase, icur);
    k_fill<<<512, 256, 0, stream>>>(ei, icur, isrcs);
    k_gather<<<8192, 256, 0, stream>>>(x, ibase, isrcs, agg);

    // h1_pre = agg@W_rel + b_rel + x@W_root + x  [S1]
    gemm_k<true, 0, true><<<dim3(512, 2), 256, 0, stream>>>(
        agg, W_rel, x, W_root, NROWS, 128, 128, 128, 128,
        b_rel, x, 128, h1p, st + 0, st + 128);
    // xz = x @ in_W
    gemm_k<false, 0, false><<<dim3(512, 8), 256, 0, stream>>>(
        x, in_W, nullptr, nullptr, NROWS, 512, 128, 512, 512,
        nullptr, nullptr, 0, xz, nullptr, nullptr);
    k_conv<<<32768, 256, 0, stream>>>(xz, conv_w, conv_b, xc);
    // proj = xc @ xproj_W (N=40)
    gemm_k<false, 0, false><<<dim3(512, 1), 256, 0, stream>>>(
        xc, xproj_W, nullptr, nullptr, NROWS, 40, 256, 40, 40,
        nullptr, nullptr, 0, proj, nullptr, nullptr);
    k_dtbc<<<1024, 256, 0, stream>>>(proj, dt_W, dt_b, dtb, Bc, Cc);
    k_scan<<<256, 256, 0, stream>>>(dtb, xc, xz, Bc, Cc, A_log, Dp, ygb);
    // p2 = yg @ out_W + x  [S2]
    gemm_k<false, 0, true><<<dim3(512, 2), 256, 0, stream>>>(
        ygb, out_W, nullptr, nullptr, NROWS, 128, 256, 128, 128,
        nullptr, x, 128, p2, st + 256, st + 384);
    k_fin12<<<1, 256, 0, stream>>>(st, n1_g, n1_b, n2_g, n2_b, ab);
    // out = BN1(h1_pre) + BN2(p2)  [S3]
    k_add<<<512, 256, 0, stream>>>(h1p, p2, ab, outb, st + 512, st + 640);
    k_fin3_fold1<<<1, 256, 0, stream>>>(st + 512, st + 640, m1_g, m1_b, W1, b1, W1e, b1e);
    // g = gelu(out @ W1e + b1e)  [S4]
    gemm_k<false, 1, true><<<dim3(512, 4), 256, 0, stream>>>(
        outb, W1e, nullptr, nullptr, NROWS, 256, 128, 256, 256,
        b1e, nullptr, 0, gbuf, st + 768, st + 1024);
    k_fin4_fold2<<<1, 256, 0, stream>>>(st + 768, st + 1024, m2_g, m2_b, W2, b2, W2e, b2e);
    // out2 = g @ W2e + b2e + out  [S5]
    gemm_k<false, 0, true><<<dim3(512, 2), 256, 0, stream>>>(
        gbuf, W2e, nullptr, nullptr, NROWS, 128, 256, 128, 128,
        b2e, outb, 128, out2, st + 1280, st + 1408);
    k_fin5<<<1, 128, 0, stream>>>(st + 1280, st + 1408, n3_g, n3_b, ab);
    k_bn3<<<4096, 256, 0, stream>>>(out2, ab, (float*)d_out);
}

// Round 3
// 698.143 us; speedup vs baseline: 1.2374x; 1.0762x over previous
//
#include <hip/hip_runtime.h>

// ---------------------------------------------------------------------------
// GraphMambaConv: N=32768 nodes, C=128, G=64 graphs x L=512, E=524288 edges,
// D_INNER=256, D_STATE=16, DT_RANK=8, D_CONV=4.  All fp32.
//
// Round 3: k_scan was latency-bound (930 cyc/step, 1 wave/SIMD, depth-1
// prefetch << L3/HBM latency). New k_scan: 32-step LDS chunks, double
// buffered, register-staged prefetch with wave role-split. Loads for chunk
// c+1 are issued before compute of chunk c -> ~2500 cyc to land.
// ---------------------------------------------------------------------------

#define NROWS 32768
#define CDIM  128
#define EDGES 524288
#define GL    512
#define SCH   32          // scan chunk (timesteps)
#define NCH   (GL / SCH)  // 16 chunks

// ------------------------- CSR build: histogram ----------------------------
__global__ __launch_bounds__(256) void k_hist(const int* __restrict__ ei,
                                              int* __restrict__ deg)
{
    const int e = blockIdx.x * 1024 + threadIdx.x * 4;
    const int4 d4 = *(const int4*)&ei[EDGES + e];
    atomicAdd(&deg[d4.x], 1);
    atomicAdd(&deg[d4.y], 1);
    atomicAdd(&deg[d4.z], 1);
    atomicAdd(&deg[d4.w], 1);
}

// ---------------- CSR build: exclusive prefix scan (1 block) ---------------
__global__ __launch_bounds__(1024) void k_scanidx(const int* __restrict__ deg,
                                                  int* __restrict__ base,
                                                  int* __restrict__ cursor)
{
    __shared__ int ps[1024];
    const int tid = threadIdx.x;
    int loc[32];
    int s = 0;
#pragma unroll
    for (int i = 0; i < 32; ++i) { loc[i] = deg[tid * 32 + i]; s += loc[i]; }
    ps[tid] = s;
    __syncthreads();
    for (int off = 1; off < 1024; off <<= 1) {
        int v = (tid >= off) ? ps[tid - off] : 0;
        __syncthreads();
        ps[tid] += v;
        __syncthreads();
    }
    int run = tid ? ps[tid - 1] : 0;
#pragma unroll
    for (int i = 0; i < 32; ++i) {
        base[tid * 32 + i] = run;
        cursor[tid * 32 + i] = run;
        run += loc[i];
    }
    if (tid == 0) base[32768] = EDGES;
}

// ------------------------- CSR build: fill src lists -----------------------
__global__ __launch_bounds__(256) void k_fill(const int* __restrict__ ei,
                                              int* __restrict__ cursor,
                                              int* __restrict__ srcs)
{
    const int e = blockIdx.x * 1024 + threadIdx.x * 4;
    const int4 s4 = *(const int4*)&ei[e];
    const int4 d4 = *(const int4*)&ei[EDGES + e];
    int p;
    p = atomicAdd(&cursor[d4.x], 1); srcs[p] = s4.x;
    p = atomicAdd(&cursor[d4.y], 1); srcs[p] = s4.y;
    p = atomicAdd(&cursor[d4.z], 1); srcs[p] = s4.z;
    p = atomicAdd(&cursor[d4.w], 1); srcs[p] = s4.w;
}

// ------------------------- gather: one wave per node ------------------------
__global__ __launch_bounds__(256) void k_gather(const float* __restrict__ x,
                                                const int* __restrict__ base,
                                                const int* __restrict__ srcs,
                                                float* __restrict__ agg)
{
    const int node = blockIdx.x * 4 + (threadIdx.x >> 6);
    const int lane = threadIdx.x & 63;
    const int b0 = base[node], b1 = base[node + 1];
    float2 a0 = make_float2(0.f, 0.f), a1 = make_float2(0.f, 0.f);
    int i = b0;
    for (; i + 2 <= b1; i += 2) {
        const int s0 = srcs[i], s1 = srcs[i + 1];
        const float2 v0 = *(const float2*)&x[(size_t)s0 * 128 + lane * 2];
        const float2 v1 = *(const float2*)&x[(size_t)s1 * 128 + lane * 2];
        a0.x += v0.x; a0.y += v0.y;
        a1.x += v1.x; a1.y += v1.y;
    }
    if (i < b1) {
        const int s0 = srcs[i];
        const float2 v0 = *(const float2*)&x[(size_t)s0 * 128 + lane * 2];
        a0.x += v0.x; a0.y += v0.y;
    }
    a0.x += a1.x; a0.y += a1.y;
    *(float2*)&agg[(size_t)node * 128 + lane * 2] = a0;
}

// ------------------------------ GEMM core ---------------------------------
// out = epi( A0@W0 [+ A1@W1] [+bias] [+resid] ), optional column stats.
// A is MxK row-major (lda=K), W is KxN row-major (ldw), tile 64x64, 4x4/thread.
#define TM 64
#define TN 64
#define KB 32

template<bool DUAL, int ACT, bool STAT>
__global__ __launch_bounds__(256)
void gemm_k(const float* __restrict__ A0, const float* __restrict__ W0,
            const float* __restrict__ A1p, const float* __restrict__ W1p,
            int M, int N, int K, int ldw, int ldo,
            const float* __restrict__ bias,
            const float* __restrict__ resid, int ldr,
            float* __restrict__ outp,
            float* __restrict__ sumP, float* __restrict__ sqP)
{
    __shared__ __align__(16) float As[KB][TM];
    __shared__ __align__(16) float Bs[KB][TN];
    __shared__ float sB[2][TN];

    const int m0 = blockIdx.x * TM;
    const int n0 = blockIdx.y * TN;
    const int tid = threadIdx.x;
    const int tx = tid & 15;         // -> 4 cols
    const int ty = tid >> 4;         // -> 4 rows

    float acc[4][4];
#pragma unroll
    for (int i = 0; i < 4; ++i)
#pragma unroll
        for (int j = 0; j < 4; ++j) acc[i][j] = 0.f;

    const int npass = DUAL ? 2 : 1;
    for (int pass = 0; pass < npass; ++pass) {
        const float* A = (DUAL && pass) ? A1p : A0;
        const float* W = (DUAL && pass) ? W1p : W0;
        for (int k0 = 0; k0 < K; k0 += KB) {
            {   // A tile: rows m0..+64, cols k0..+32 ; store transposed
                int m = tid & 63, kg = tid >> 6;
                const float* src = A + (size_t)(m0 + m) * K + k0 + kg * 8;
                float4 v0 = *(const float4*)(src);
                float4 v1 = *(const float4*)(src + 4);
                int kb = kg * 8;
                As[kb + 0][m] = v0.x; As[kb + 1][m] = v0.y;
                As[kb + 2][m] = v0.z; As[kb + 3][m] = v0.w;
                As[kb + 4][m] = v1.x; As[kb + 5][m] = v1.y;
                As[kb + 6][m] = v1.z; As[kb + 7][m] = v1.w;
            }
            {   // W tile: rows k0..+32, cols n0..+64 (zero-pad n>=N)
                int n = tid & 63, kg = tid >> 6;
                int nn = n0 + n;
#pragma unroll
                for (int j = 0; j < 8; ++j) {
                    int k = k0 + kg * 8 + j;
                    Bs[kg * 8 + j][n] = (nn < N) ? W[(size_t)k * ldw + nn] : 0.f;
                }
            }
            __syncthreads();
#pragma unroll
            for (int kb = 0; kb < KB; ++kb) {
                const float4 av = *(const float4*)&As[kb][ty * 4];
                const float4 bv = *(const float4*)&Bs[kb][tx * 4];
                const float aa[4] = {av.x, av.y, av.z, av.w};
                const float bb[4] = {bv.x, bv.y, bv.z, bv.w};
#pragma unroll
                for (int i = 0; i < 4; ++i)
#pragma unroll
                    for (int j = 0; j < 4; ++j) acc[i][j] += aa[i] * bb[j];
            }
            __syncthreads();
        }
    }

    // ------------------------------ epilogue ------------------------------
    const int r0 = m0 + ty * 4;
    const int c0 = n0 + tx * 4;
    const bool cok = (c0 + 4 <= N);
    float cs[4] = {0.f, 0.f, 0.f, 0.f}, cq[4] = {0.f, 0.f, 0.f, 0.f};
    if (cok) {
        float bv[4] = {0.f, 0.f, 0.f, 0.f};
        if (bias) { float4 t = *(const float4*)&bias[c0];
                    bv[0] = t.x; bv[1] = t.y; bv[2] = t.z; bv[3] = t.w; }
#pragma unroll
        for (int i = 0; i < 4; ++i) {
            float v[4];
#pragma unroll
            for (int j = 0; j < 4; ++j) v[j] = acc[i][j] + bv[j];
            if (resid) {
                float4 rv = *(const float4*)&resid[(size_t)(r0 + i) * ldr + c0];
                v[0] += rv.x; v[1] += rv.y; v[2] += rv.z; v[3] += rv.w;
            }
            if (ACT == 1) {   // exact GELU
#pragma unroll
                for (int j = 0; j < 4; ++j)
                    v[j] = 0.5f * v[j] * (1.f + erff(v[j] * 0.7071067811865475f));
            }
            *(float4*)&outp[(size_t)(r0 + i) * ldo + c0] =
                make_float4(v[0], v[1], v[2], v[3]);
            if (STAT) {
#pragma unroll
                for (int j = 0; j < 4; ++j) { cs[j] += v[j]; cq[j] += v[j] * v[j]; }
            }
        }
    }
    if (STAT) {
        if (tid < TN) { sB[0][tid] = 0.f; sB[1][tid] = 0.f; }
        __syncthreads();
        if (cok) {
#pragma unroll
            for (int j = 0; j < 4; ++j) {
                atomicAdd(&sB[0][tx * 4 + j], cs[j]);
                atomicAdd(&sB[1][tx * 4 + j], cq[j]);
            }
        }
        __syncthreads();
        if (tid < TN && (n0 + tid) < N) {
            atomicAdd(&sumP[n0 + tid], sB[0][tid]);
            atomicAdd(&sqP[n0 + tid],  sB[1][tid]);
        }
    }
}

// --------------------------- causal conv + SiLU ----------------------------
__global__ __launch_bounds__(256) void k_conv(const float* __restrict__ xz,
                                              const float* __restrict__ cw,
                                              const float* __restrict__ cb,
                                              float* __restrict__ xc)
{
    const int r = blockIdx.x;        // global row
    const int l = r & (GL - 1);      // position within graph
    const int d = threadIdx.x;       // 0..255
    float4 w4 = *(const float4*)&cw[d * 4];
    const float taps[4] = {w4.x, w4.y, w4.z, w4.w};
    float acc = cb[d];
#pragma unroll
    for (int k = 0; k < 4; ++k) {
        int ll = l - 3 + k;
        if (ll >= 0) acc += xz[(size_t)(r - 3 + k) * 512 + d] * taps[k];
    }
    float s = 1.f / (1.f + __expf(-acc));
    xc[(size_t)r * 256 + d] = acc * s;
}

// ---------------- dt = softplus(proj[:,:8] @ dt_W + dt_b); B,C slices ------
__global__ __launch_bounds__(256) void k_dtbc(const float* __restrict__ proj,
                                              const float* __restrict__ dt_W,
                                              const float* __restrict__ dt_b,
                                              float* __restrict__ dtb,
                                              float* __restrict__ Bc,
                                              float* __restrict__ Cc)
{
    __shared__ float dtWS[8 * 256];
    __shared__ float dt_bS[256];
    __shared__ float projS[32 * 8];
    const int tid = threadIdx.x;
    const int r0 = blockIdx.x * 32;
    for (int i = tid; i < 2048; i += 256) dtWS[i] = dt_W[i];
    dt_bS[tid] = dt_b[tid];
    projS[tid] = proj[(size_t)(r0 + (tid >> 3)) * 40 + (tid & 7)];
    __syncthreads();

    const int c = tid;
    for (int rr = 0; rr < 32; ++rr) {
        float acc = dt_bS[c];
        const float* pr = &projS[rr * 8];
#pragma unroll
        for (int q = 0; q < 8; ++q) acc += pr[q] * dtWS[q * 256 + c];
        float sp = fmaxf(acc, 0.f) + log1pf(__expf(-fabsf(acc)));
        dtb[(size_t)(r0 + rr) * 256 + c] = sp;
    }
    // B = proj[:, 8:24], C = proj[:, 24:40]
    for (int e = tid; e < 1024; e += 256) {
        int rr = e >> 5, cc = e & 31;
        float v = proj[(size_t)(r0 + rr) * 40 + 8 + cc];
        if (cc < 16) Bc[(size_t)(r0 + rr) * 16 + cc] = v;
        else         Cc[(size_t)(r0 + rr) * 16 + cc - 16] = v;
    }
}

// ------------------------------ selective scan -----------------------------
// Chunked LDS pipeline. Block = (g, dblk): 64 d-channels, 4 lanes (states) per
// d. Per 32-step chunk: wave0 stages dt, wave1 xc, wave2 z, wave3 B+C into
// LDS (register-staged, issued one chunk ahead -> ~2500 cyc to cover HBM/L3
// latency). One __syncthreads per chunk (buf[c&1] reuse is 2 barriers away).
// NOTE: yg aliases dtb — chunk c+1's dtb rows are loaded to regs before any
// chunk-c yg writes; each block touches only its own (g, d-slice) rows.
__global__ __launch_bounds__(256) void k_scan(const float* __restrict__ dtb,
                                              const float* __restrict__ xcb,
                                              const float* __restrict__ xzb,
                                              const float* __restrict__ Bb,
                                              const float* __restrict__ Cb,
                                              const float* __restrict__ A_log,
                                              const float* __restrict__ Dp,
                                              float* __restrict__ yg)
{
    // per buffer: dt[32][64] | xc[32][64] | z[32][64] | B[32][16] | C[32][16]
    __shared__ __align__(16) float buf[2][SCH * 224];

    const int g    = blockIdx.x >> 2;
    const int dblk = blockIdx.x & 3;
    const int tid  = threadIdx.x;
    const int wave = tid >> 6, lane = tid & 63;
    const int dl = tid >> 2, sq = tid & 3;   // local d (0..63), state quad
    const int d0 = dblk * 64;
    const int d  = d0 + dl;
    const size_t rbase = (size_t)g * GL;

    float aA[4];
    {
        float4 t = *(const float4*)(A_log + d * 16 + sq * 4);
        aA[0] = -__expf(t.x); aA[1] = -__expf(t.y);
        aA[2] = -__expf(t.z); aA[3] = -__expf(t.w);
    }
    const float Dpd = Dp[d];
    float h[4] = {0.f, 0.f, 0.f, 0.f};

    float4 rg[8];
    const int lr  = lane >> 4, lc = lane & 15;   // dt/xc/z staging coords
    const int br  = lane >> 2, bc = lane & 3;    // B/C staging coords

    // ---- load chunk 0 into registers ----
    {
        const size_t r0 = rbase;
        if (wave == 0) {
#pragma unroll
            for (int k = 0; k < 8; ++k)
                rg[k] = *(const float4*)&dtb[(r0 + k * 4 + lr) * 256 + d0 + lc * 4];
        } else if (wave == 1) {
#pragma unroll
            for (int k = 0; k < 8; ++k)
                rg[k] = *(const float4*)&xcb[(r0 + k * 4 + lr) * 256 + d0 + lc * 4];
        } else if (wave == 2) {
#pragma unroll
            for (int k = 0; k < 8; ++k)
                rg[k] = *(const float4*)&xzb[(r0 + k * 4 + lr) * 512 + 256 + d0 + lc * 4];
        } else {
#pragma unroll
            for (int k = 0; k < 2; ++k) {
                rg[k]     = *(const float4*)&Bb[(r0 + k * 16 + br) * 16 + bc * 4];
                rg[2 + k] = *(const float4*)&Cb[(r0 + k * 16 + br) * 16 + bc * 4];
            }
        }
    }

    for (int c = 0; c < NCH; ++c) {
        float* bufc = buf[c & 1];
        // ---- commit staged registers to LDS ----
        if (wave == 0) {
#pragma unroll
            for (int k = 0; k < 8; ++k)
                *(float4*)&bufc[(k * 4 + lr) * 64 + lc * 4] = rg[k];
        } else if (wave == 1) {
#pragma unroll
            for (int k = 0; k < 8; ++k)
                *(float4*)&bufc[2048 + (k * 4 + lr) * 64 + lc * 4] = rg[k];
        } else if (wave == 2) {
#pragma unroll
            for (int k = 0; k < 8; ++k)
                *(float4*)&bufc[4096 + (k * 4 + lr) * 64 + lc * 4] = rg[k];
        } else {
#pragma unroll
            for (int k = 0; k < 2; ++k) {
                *(float4*)&bufc[6144 + (k * 16 + br) * 16 + bc * 4] = rg[k];
                *(float4*)&bufc[6656 + (k * 16 + br) * 16 + bc * 4] = rg[2 + k];
            }
        }
        __syncthreads();

        // ---- issue next chunk's loads (consumed after ~32 steps) ----
        if (c + 1 < NCH) {
            const size_t r0 = rbase + (size_t)(c + 1) * SCH;
            if (wave == 0) {
#pragma unroll
                for (int k = 0; k < 8; ++k)
                    rg[k] = *(const float4*)&dtb[(r0 + k * 4 + lr) * 256 + d0 + lc * 4];
            } else if (wave == 1) {
#pragma unroll
                for (int k = 0; k < 8; ++k)
                    rg[k] = *(const float4*)&xcb[(r0 + k * 4 + lr) * 256 + d0 + lc * 4];
            } else if (wave == 2) {
#pragma unroll
                for (int k = 0; k < 8; ++k)
                    rg[k] = *(const float4*)&xzb[(r0 + k * 4 + lr) * 512 + 256 + d0 + lc * 4];
            } else {
#pragma unroll
                for (int k = 0; k < 2; ++k) {
                    rg[k]     = *(const float4*)&Bb[(r0 + k * 16 + br) * 16 + bc * 4];
                    rg[2 + k] = *(const float4*)&Cb[(r0 + k * 16 + br) * 16 + bc * 4];
                }
            }
        }

        // ---- 32 scan steps from LDS ----
        const float* pdt = bufc;
        const float* pxc = bufc + 2048;
        const float* pz  = bufc + 4096;
        const float* pB  = bufc + 6144;
        const float* pC  = bufc + 6656;
        const size_t rr0 = rbase + (size_t)c * SCH;
#pragma unroll 4
        for (int t = 0; t < SCH; ++t) {
            const float dt = pdt[t * 64 + dl];
            const float xc = pxc[t * 64 + dl];
            const float z  = pz [t * 64 + dl];
            const float4 Bv = *(const float4*)&pB[t * 16 + sq * 4];
            const float4 Cv = *(const float4*)&pC[t * 16 + sq * 4];
            const float dtx = dt * xc;
            h[0] = h[0] * __expf(dt * aA[0]) + dtx * Bv.x;
            h[1] = h[1] * __expf(dt * aA[1]) + dtx * Bv.y;
            h[2] = h[2] * __expf(dt * aA[2]) + dtx * Bv.z;
            h[3] = h[3] * __expf(dt * aA[3]) + dtx * Bv.w;
            float y = h[0] * Cv.x + h[1] * Cv.y + h[2] * Cv.z + h[3] * Cv.w;
            y += __shfl_xor(y, 1);
            y += __shfl_xor(y, 2);
            if (sq == 0) {
                const float sz = z / (1.f + __expf(-z));
                yg[(rr0 + t) * 256 + d] = (y + xc * Dpd) * sz;
            }
        }
        // no trailing barrier needed: buf[c&1] is rewritten only at chunk c+2,
        // whose ds_writes are preceded by chunk c+1's barrier.
    }
}

// -------------------------- BN finalize / fold / add -----------------------
__global__ __launch_bounds__(256) void k_fin12(const float* __restrict__ st,
                                               const float* g1, const float* be1,
                                               const float* g2, const float* be2,
                                               float* __restrict__ ab)
{
    const int tid = threadIdx.x;
    const float inv = 1.f / 32768.f;
    if (tid < 128) {
        float m = st[tid] * inv, v = st[128 + tid] * inv - m * m;
        float a = g1[tid] * rsqrtf(v + 1e-5f);
        ab[tid] = a; ab[256 + tid] = be1[tid] - m * a;
    } else {
        int c = tid - 128;
        float m = st[256 + c] * inv, v = st[384 + c] * inv - m * m;
        float a = g2[c] * rsqrtf(v + 1e-5f);
        ab[512 + c] = a; ab[768 + c] = be2[c] - m * a;
    }
}

__global__ __launch_bounds__(256) void k_add(const float* __restrict__ h1p,
                                             const float* __restrict__ p2,
                                             const float* __restrict__ ab,
                                             float* __restrict__ outp,
                                             float* __restrict__ sumP,
                                             float* __restrict__ sqP)
{
    const int c = threadIdx.x & 127, half = threadIdx.x >> 7;
    const int rbase = blockIdx.x * 64 + half * 32;
    const float a1 = ab[c], b1 = ab[256 + c], a2 = ab[512 + c], b2 = ab[768 + c];
    float s = 0.f, q = 0.f;
    for (int i = 0; i < 32; ++i) {
        size_t idx = (size_t)(rbase + i) * 128 + c;
        float v = h1p[idx] * a1 + b1 + p2[idx] * a2 + b2;
        outp[idx] = v; s += v; q += v * v;
    }
    __shared__ float sh[2][2][128];
    sh[0][half][c] = s; sh[1][half][c] = q;
    __syncthreads();
    if (threadIdx.x < 128) {
        atomicAdd(&sumP[c], sh[0][0][c] + sh[0][1][c]);
        atomicAdd(&sqP[c],  sh[1][0][c] + sh[1][1][c]);
    }
}

__global__ __launch_bounds__(256) void k_fin3_fold1(
    const float* __restrict__ sumP, const float* __restrict__ sqP,
    const float* __restrict__ gam, const float* __restrict__ bet,
    const float* __restrict__ W1, const float* __restrict__ b1in,
    float* __restrict__ W1e, float* __restrict__ b1e)
{
    __shared__ float aS[128], bS[128];
    const int tid = threadIdx.x;
    const float inv = 1.f / 32768.f;
    if (tid < 128) {
        float m = sumP[tid] * inv, v = sqP[tid] * inv - m * m;
        float a = gam[tid] * rsqrtf(v + 1e-5f);
        aS[tid] = a; bS[tid] = bet[tid] - m * a;
    }
    __syncthreads();
    for (int e = tid; e < 128 * 256; e += 256) W1e[e] = aS[e >> 8] * W1[e];
    float acc = b1in[tid];
    for (int k = 0; k < 128; ++k) acc += bS[k] * W1[k * 256 + tid];
    b1e[tid] = acc;
}

__global__ __launch_bounds__(256) void k_fin4_fold2(
    const float* __restrict__ sumP, const float* __restrict__ sqP,
    const float* __restrict__ gam, const float* __restrict__ bet,
    const float* __restrict__ W2, const float* __restrict__ b2in,
    float* __restrict__ W2e, float* __restrict__ b2e)
{
    __shared__ float aS[256], bS[256];
    const int tid = threadIdx.x;
    const float inv = 1.f / 32768.f;
    {
        float m = sumP[tid] * inv, v = sqP[tid] * inv - m * m;
        float a = gam[tid] * rsqrtf(v + 1e-5f);
        aS[tid] = a; bS[tid] = bet[tid] - m * a;
    }
    __syncthreads();
    for (int e = tid; e < 256 * 128; e += 256) W2e[e] = aS[e >> 7] * W2[e];
    if (tid < 128) {
        float acc = b2in[tid];
        for (int k = 0; k < 256; ++k) acc += bS[k] * W2[k * 128 + tid];
        b2e[tid] = acc;
    }
}

__global__ __launch_bounds__(128) void k_fin5(const float* __restrict__ sumP,
                                              const float* __restrict__ sqP,
                                              const float* gam, const float* bet,
                                              float* __restrict__ ab)
{
    const int tid = threadIdx.x;
    if (tid < 128) {
        const float inv = 1.f / 32768.f;
        float m = sumP[tid] * inv, v = sqP[tid] * inv - m * m;
        float a = gam[tid] * rsqrtf(v + 1e-5f);
        ab[2048 + tid] = a; ab[2304 + tid] = bet[tid] - m * a;
    }
}

__global__ __launch_bounds__(256) void k_bn3(const float* __restrict__ out2,
                                             const float* __restrict__ ab,
                                             float* __restrict__ dout)
{
    size_t i4 = ((size_t)blockIdx.x * 256 + threadIdx.x) * 4;
    int c = (int)(i4 & 127);
    float4 v = *(const float4*)&out2[i4];
    float4 a = *(const float4*)&ab[2048 + c];
    float4 b = *(const float4*)&ab[2304 + c];
    v.x = v.x * a.x + b.x; v.y = v.y * a.y + b.y;
    v.z = v.z * a.z + b.z; v.w = v.w * a.w + b.w;
    *(float4*)&dout[i4] = v;
}

// ------------------------------- launch ------------------------------------
extern "C" void kernel_launch(void* const* d_in, const int* in_sizes, int n_in,
                              void* d_out, int out_size, void* d_ws, size_t ws_size,
                              hipStream_t stream)
{
    (void)in_sizes; (void)n_in; (void)out_size; (void)ws_size;
    const float* x      = (const float*)d_in[0];
    const int*   ei     = (const int*)d_in[1];
    // d_in[2] = batch (unused: equal-size sorted graphs == reshape)
    const float* W_root = (const float*)d_in[3];
    const float* W_rel  = (const float*)d_in[4];
    const float* b_rel  = (const float*)d_in[5];
    const float* n1_g = (const float*)d_in[6],  *n1_b = (const float*)d_in[7];
    const float* n2_g = (const float*)d_in[8],  *n2_b = (const float*)d_in[9];
    const float* n3_g = (const float*)d_in[10], *n3_b = (const float*)d_in[11];
    const float* m1_g = (const float*)d_in[12], *m1_b = (const float*)d_in[13];
    const float* W1   = (const float*)d_in[14], *b1   = (const float*)d_in[15];
    const float* m2_g = (const float*)d_in[16], *m2_b = (const float*)d_in[17];
    const float* W2   = (const float*)d_in[18], *b2   = (const float*)d_in[19];
    const float* in_W   = (const float*)d_in[20];
    const float* conv_w = (const float*)d_in[21], *conv_b = (const float*)d_in[22];
    const float* xproj_W= (const float*)d_in[23];
    const float* dt_W   = (const float*)d_in[24], *dt_b = (const float*)d_in[25];
    const float* A_log  = (const float*)d_in[26], *Dp   = (const float*)d_in[27];
    const float* out_W  = (const float*)d_in[28];

    float* ws = (float*)d_ws;
    // small region
    float* st  = ws;             // 2048 used (S1..S5 sums/sumsqs)
    float* ab  = ws + 4096;      // a/b affine params
    float* W1e = ws + 8192;      // 128*256
    float* b1e = W1e + 32768;    // 256
    float* W2e = ws + 41216;     // 256*128
    float* b2e = W2e + 32768;    // 128
    // big buffers (base aligned; ~194 MB total)
    float* big  = ws + 74752;
    float* agg  = big;                    // 4194304 (later reused as p2)
    float* p2   = agg;
    float* h1p  = big + 4194304;          // 4194304
    float* xz   = big + 8388608;          // 16777216 (later: g + out2)
    float* gbuf = xz;
    float* out2 = xz + 8388608;
    float* xc   = big + 25165824;         // 8388608
    float* proj = big + 33554432;         // 1310720
    float* dtb  = big + 34865152;         // 8388608 (yg aliases dtb)
    float* ygb  = dtb;
    float* Bc   = big + 43253760;         // 524288
    float* Cc   = big + 43778048;         // 524288
    float* outb = big + 44302336;         // 4194304

    // CSR scratch lives in the h1p region (dead until the h1 GEMM writes it):
    // gather (last CSR reader) completes before gemm h1 (first h1p writer).
    int* ideg   = (int*)h1p;              // 32768
    int* ibase  = ideg + 32768;           // 32769
    int* icur   = ideg + 65552;           // 32768 (16B-aligned)
    int* isrcs  = ideg + 98320;           // 524288

    hipMemsetAsync(st, 0, 2048 * sizeof(float), stream);
    hipMemsetAsync(ideg, 0, 32768 * sizeof(int), stream);

    // ---- CSR build + gather (replaces atomic scatter) ----
    k_hist<<<512, 256, 0, stream>>>(ei, ideg);
    k_scanidx<<<1, 1024, 0, stream>>>(ideg, ibase, icur);
    k_fill<<<512, 256, 0, stream>>>(ei, icur, isrcs);
    k_gather<<<8192, 256, 0, stream>>>(x, ibase, isrcs, agg);

    // h1_pre = agg@W_rel + b_rel + x@W_root + x  [S1]
    gemm_k<true, 0, true><<<dim3(512, 2), 256, 0, stream>>>(
        agg, W_rel, x, W_root, NROWS, 128, 128, 128, 128,
        b_rel, x, 128, h1p, st + 0, st + 128);
    // xz = x @ in_W
    gemm_k<false, 0, false><<<dim3(512, 8), 256, 0, stream>>>(
        x, in_W, nullptr, nullptr, NROWS, 512, 128, 512, 512,
        nullptr, nullptr, 0, xz, nullptr, nullptr);
    k_conv<<<32768, 256, 0, stream>>>(xz, conv_w, conv_b, xc);
    // proj = xc @ xproj_W (N=40)
    gemm_k<false, 0, false><<<dim3(512, 1), 256, 0, stream>>>(
        xc, xproj_W, nullptr, nullptr, NROWS, 40, 256, 40, 40,
        nullptr, nullptr, 0, proj, nullptr, nullptr);
    k_dtbc<<<1024, 256, 0, stream>>>(proj, dt_W, dt_b, dtb, Bc, Cc);
    k_scan<<<256, 256, 0, stream>>>(dtb, xc, xz, Bc, Cc, A_log, Dp, ygb);
    // p2 = yg @ out_W + x  [S2]
    gemm_k<false, 0, true><<<dim3(512, 2), 256, 0, stream>>>(
        ygb, out_W, nullptr, nullptr, NROWS, 128, 256, 128, 128,
        nullptr, x, 128, p2, st + 256, st + 384);
    k_fin12<<<1, 256, 0, stream>>>(st, n1_g, n1_b, n2_g, n2_b, ab);
    // out = BN1(h1_pre) + BN2(p2)  [S3]
    k_add<<<512, 256, 0, stream>>>(h1p, p2, ab, outb, st + 512, st + 640);
    k_fin3_fold1<<<1, 256, 0, stream>>>(st + 512, st + 640, m1_g, m1_b, W1, b1, W1e, b1e);
    // g = gelu(out @ W1e + b1e)  [S4]
    gemm_k<false, 1, true><<<dim3(512, 4), 256, 0, stream>>>(
        outb, W1e, nullptr, nullptr, NROWS, 256, 128, 256, 256,
        b1e, nullptr, 0, gbuf, st + 768, st + 1024);
    k_fin4_fold2<<<1, 256, 0, stream>>>(st + 768, st + 1024, m2_g, m2_b, W2, b2, W2e, b2e);
    // out2 = g @ W2e + b2e + out  [S5]
    gemm_k<false, 0, true><<<dim3(512, 2), 256, 0, stream>>>(
        gbuf, W2e, nullptr, nullptr, NROWS, 128, 256, 128, 128,
        b2e, outb, 128, out2, st + 1280, st + 1408);
    k_fin5<<<1, 128, 0, stream>>>(st + 1280, st + 1408, n3_g, n3_b, ab);
    k_bn3<<<4096, 256, 0, stream>>>(out2, ab, (float*)d_out);
}